// Round 1
// baseline (4208.565 us; speedup 1.0000x reference)
//
#include <hip/hip_runtime.h>

typedef _Float16 f16;
typedef _Float16 f16x8 __attribute__((ext_vector_type(8)));
typedef float f32x4 __attribute__((ext_vector_type(4)));

#define MFMA16(a, b, c) __builtin_amdgcn_mfma_f32_16x16x32_f16((a), (b), (c), 0, 0, 0)

__device__ __forceinline__ float sigmoidf_(float x) { return 1.f / (1.f + __expf(-x)); }
__device__ __forceinline__ float tanhf_(float x) { return 1.f - 2.f / (__expf(2.f * x) + 1.f); }

// ---------------- workspace layout (bytes) ----------------
// packed fp16 weights (element offsets within pk):
//   inW 0 | e0 16384 | e1 344064 | d0i 868352 | d0h 933888 | d1 950272 | out 983040 | end 999424
#define PK_BYTES   1998848
#define BIAS_OFF   1998848   // 2560 floats: be0[1024] be1[1024] bd0[256] bd1[256]
#define H0_OFF     2009088   // 1024*100*64 f16
#define H1_OFF     15116288  // 1024*100*256 f16
#define Z_OFF      67545088  // 1024*256 f16

// Fragment-major packed weight index: group = (nt*KT + kt)*64 + lane, 8 f16 per group.
// n = nt*16 + (lane&15), k = kt*32 + (lane>>4)*8 + j   (matches gfx950 16x16x32 A/B layout)

__global__ __launch_bounds__(256) void pack_kernel(
    const float* inW,
    const float* e0i, const float* e0h, const float* e1i, const float* e1h,
    const float* d0i, const float* d0h, const float* d1i, const float* d1h,
    const float* outW,
    const float* eb0i, const float* eb0h, const float* eb1i, const float* eb1h,
    const float* db0i, const float* db0h, const float* db1i, const float* db1h,
    f16* pk, float* bias_ws)
{
    int t = blockIdx.x * 256 + threadIdx.x;
    if (t < 124928) {
        int g = t; int KT, ka, kb; const float* A; const float* B; long doff;
        if (g < 2048)        {              KT = 8;  ka = 256; kb = 0;   A = inW;  B = nullptr; doff = 0; }
        else if (g < 43008)  { g -= 2048;   KT = 10; ka = 64;  kb = 256; A = e0i;  B = e0h;     doff = 16384; }
        else if (g < 108544) { g -= 43008;  KT = 16; ka = 256; kb = 256; A = e1i;  B = e1h;     doff = 344064; }
        else if (g < 116736) { g -= 108544; KT = 8;  ka = 256; kb = 0;   A = d0i;  B = nullptr; doff = 868352; }
        else if (g < 118784) { g -= 116736; KT = 2;  ka = 64;  kb = 0;   A = d0h;  B = nullptr; doff = 933888; }
        else if (g < 122880) { g -= 118784; KT = 4;  ka = 64;  kb = 64;  A = d1i;  B = d1h;     doff = 950272; }
        else                 { g -= 122880; KT = 2;  ka = 64;  kb = 0;   A = outW; B = nullptr; doff = 983040; }
        int lane = g & 63; int gk = g >> 6;
        int kt = gk % KT;  int nt = gk / KT;
        int n  = nt * 16 + (lane & 15);
        int k0 = kt * 32 + (lane >> 4) * 8;
        f16x8 v;
        #pragma unroll
        for (int j = 0; j < 8; ++j) {
            int k = k0 + j;
            float s = (k < ka) ? A[(long)n * ka + k] : B[(long)n * kb + (k - ka)];
            v[j] = (f16)s;
        }
        *(f16x8*)(pk + doff + (long)g * 8) = v;
    } else {
        int i = t - 124928;
        if (i < 1024)      bias_ws[i] = eb0i[i] + eb0h[i];
        else if (i < 2048) bias_ws[i] = eb1i[i - 1024] + eb1h[i - 1024];
        else if (i < 2304) bias_ws[i] = db0i[i - 2048] + db0h[i - 2048];
        else if (i < 2560) bias_ws[i] = db1i[i - 2304] + db1h[i - 2304];
    }
}

// h0[m][64] = relu(x[m][:256] @ inW^T + in_b), m = b*100 + t  (102400 rows)
__global__ __launch_bounds__(256) void inproj_kernel(
    const float* __restrict__ x, const f16* __restrict__ pkInW,
    const float* __restrict__ in_b, f16* __restrict__ h0)
{
    int m0 = blockIdx.x * 16;
    int tid = threadIdx.x;
    int l = tid & 63, w = tid >> 6;   // 4 waves, wave w -> n-tile w
    int p = l & 15, q = l >> 4;
    f32x4 acc = {0.f, 0.f, 0.f, 0.f};
    const float* xrow = x + (long)(m0 + p) * 256 + q * 8;
    const f16x8* bp = (const f16x8*)pkInW + w * 8 * 64 + l;
    #pragma unroll
    for (int kt = 0; kt < 8; ++kt) {
        const float4* xa = (const float4*)(xrow + kt * 32);
        float4 x0 = xa[0], x1 = xa[1];
        f16x8 a = {(f16)x0.x, (f16)x0.y, (f16)x0.z, (f16)x0.w,
                   (f16)x1.x, (f16)x1.y, (f16)x1.z, (f16)x1.w};
        f16x8 b = bp[kt * 64];
        acc = MFMA16(a, b, acc);
    }
    int n = w * 16 + p;
    float bn = in_b[n];
    #pragma unroll
    for (int r = 0; r < 4; ++r) {
        float v = acc[r] + bn;
        v = v > 0.f ? v : 0.f;
        h0[(long)(m0 + q * 4 + r) * 64 + n] = (f16)v;
    }
}

// Persistent LSTM layer: 64 blocks x 1024 threads, block owns 16 batch rows for all T.
// Wave w (0..15) owns j-slice [w*16, w*16+16) across all 4 gates -> i,f,g,o in-lane.
// h kept in LDS in fragment-major order: element (m=b, k=j) at [(k>>5)*64 + ((k>>3)&3)*16 + m]*8 + (k&7)
template <int KTX, bool WSEQ>
__global__ __launch_bounds__(1024) void lstm_enc_kernel(
    const f16* __restrict__ xseq,   // [1024][100][KTX*32] f16
    const f16* __restrict__ pkW,    // NT=64, KT=KTX+8
    const float* __restrict__ bias, // [1024] (bi+bh)
    f16* __restrict__ hseq_out,     // [1024][100][256] if WSEQ
    f16* __restrict__ z_out)        // [1024][256] if !WSEQ
{
    constexpr int KT = KTX + 8;
    constexpr int T = 100;
    constexpr int XG = KTX * 4;      // x row length in f16x8 groups
    __shared__ __align__(16) f16 hfrag[8 * 64 * 8];
    int tid = threadIdx.x;
    int l = tid & 63, w = tid >> 6;  // 16 waves
    int p = l & 15, q = l >> 4;
    int b0 = blockIdx.x * 16;

    for (int i = tid; i < 4096; i += 1024) hfrag[i] = (f16)0.f;

    float bs[4];
    #pragma unroll
    for (int g = 0; g < 4; ++g) bs[g] = bias[g * 256 + w * 16 + p];
    float c[4] = {0.f, 0.f, 0.f, 0.f};

    const f16x8* wbase[4];
    #pragma unroll
    for (int g = 0; g < 4; ++g)
        wbase[g] = (const f16x8*)pkW + (long)(g * 16 + w) * KT * 64 + l;

    __syncthreads();

    for (int t = 0; t < T; ++t) {
        f32x4 acc[4];
        #pragma unroll
        for (int g = 0; g < 4; ++g) acc[g] = (f32x4){0.f, 0.f, 0.f, 0.f};

        // x part (global, fused input projection)
        const f16x8* xp = (const f16x8*)xseq + ((long)(b0 + p) * T + t) * XG + q;
        #pragma unroll
        for (int kt = 0; kt < KTX; ++kt) {
            f16x8 a = xp[kt * 4];
            #pragma unroll
            for (int g = 0; g < 4; ++g)
                acc[g] = MFMA16(a, wbase[g][kt * 64], acc[g]);
        }
        // h part (LDS, fragment-major: conflict-free lane-contiguous 16B)
        #pragma unroll
        for (int kt2 = 0; kt2 < 8; ++kt2) {
            f16x8 a = *(const f16x8*)&hfrag[(kt2 * 64 + l) * 8];
            int kt = KTX + kt2;
            #pragma unroll
            for (int g = 0; g < 4; ++g)
                acc[g] = MFMA16(a, wbase[g][kt * 64], acc[g]);
        }
        __syncthreads();   // all h reads done before overwrite
        // pointwise, fully in-lane: lane holds i,f,g,o for (b=4q+r, j=w*16+p)
        #pragma unroll
        for (int r = 0; r < 4; ++r) {
            float iv = sigmoidf_(acc[0][r] + bs[0]);
            float fv = sigmoidf_(acc[1][r] + bs[1]);
            float gv = tanhf_(acc[2][r] + bs[2]);
            float ov = sigmoidf_(acc[3][r] + bs[3]);
            float cv = fv * c[r] + iv * gv;
            c[r] = cv;
            float hv = ov * tanhf_(cv);
            f16 hb = (f16)hv;
            int j = w * 16 + p;
            int b = q * 4 + r;
            hfrag[((j >> 5) * 64 + ((j >> 3) & 3) * 16 + b) * 8 + (j & 7)] = hb;
            if constexpr (WSEQ)
                hseq_out[((long)(b0 + b) * T + t) * 256 + j] = hb;
        }
        __syncthreads();   // h writes visible before next step's reads
    }
    if constexpr (!WSEQ) {
        for (int i = tid; i < 4096; i += 1024) {
            int b = i >> 8, j = i & 255;
            z_out[(long)(b0 + b) * 256 + j] =
                hfrag[((j >> 5) * 64 + ((j >> 3) & 3) * 16 + b) * 8 + (j & 7)];
        }
    }
}

// Fused decoder: dec0 (input z, constant over t -> xz in regs) + dec1 + output projection.
// 64 blocks x 256 threads (4 waves). hdfrag holds [h_d0 | h_d1] (K=128) fragment-major.
__global__ __launch_bounds__(256) void lstm_dec_kernel(
    const f16* __restrict__ z,
    const f16* __restrict__ pkD0i, const f16* __restrict__ pkD0h,
    const f16* __restrict__ pkD1,  const f16* __restrict__ pkOut,
    const float* __restrict__ bd0, const float* __restrict__ bd1,
    const float* __restrict__ out_b, float* __restrict__ out)
{
    constexpr int T = 100;
    __shared__ __align__(16) f16 hdfrag[4 * 64 * 8];
    int tid = threadIdx.x;
    int l = tid & 63, w = tid >> 6;  // 4 waves, wave w -> j-slice [w*16, w*16+16)
    int p = l & 15, q = l >> 4;
    int b0 = blockIdx.x * 16;

    for (int i = tid; i < 2048; i += 256) hdfrag[i] = (f16)0.f;

    // xz = z @ dW0i^T + bd0  (constant over t), kept in registers
    f32x4 xz[4];
    #pragma unroll
    for (int g = 0; g < 4; ++g) xz[g] = (f32x4){0.f, 0.f, 0.f, 0.f};
    {
        const f16x8* zp = (const f16x8*)z + (long)(b0 + p) * 32 + q;
        const f16x8* wp = (const f16x8*)pkD0i + l;
        #pragma unroll
        for (int kt = 0; kt < 8; ++kt) {
            f16x8 a = zp[kt * 4];
            #pragma unroll
            for (int g = 0; g < 4; ++g)
                xz[g] = MFMA16(a, wp[((g * 4 + w) * 8 + kt) * 64], xz[g]);
        }
        #pragma unroll
        for (int g = 0; g < 4; ++g) {
            float bb = bd0[g * 64 + w * 16 + p];
            #pragma unroll
            for (int r = 0; r < 4; ++r) xz[g][r] += bb;
        }
    }
    float bs1[4], bso[4];
    #pragma unroll
    for (int g = 0; g < 4; ++g) bs1[g] = bd1[g * 64 + w * 16 + p];
    #pragma unroll
    for (int i = 0; i < 4; ++i) bso[i] = out_b[(w * 4 + i) * 16 + p];
    float c0[4] = {0.f, 0.f, 0.f, 0.f}, c1[4] = {0.f, 0.f, 0.f, 0.f};
    __syncthreads();

    for (int t = 0; t < T; ++t) {
        // dec0 gates: K=64 (h_d0 in hdfrag kt 0..1)
        f32x4 acc[4];
        #pragma unroll
        for (int g = 0; g < 4; ++g) acc[g] = (f32x4){0.f, 0.f, 0.f, 0.f};
        #pragma unroll
        for (int kt = 0; kt < 2; ++kt) {
            f16x8 a = *(const f16x8*)&hdfrag[(kt * 64 + l) * 8];
            #pragma unroll
            for (int g = 0; g < 4; ++g)
                acc[g] = MFMA16(a, ((const f16x8*)pkD0h)[(((g * 4 + w) * 2 + kt) * 64) + l], acc[g]);
        }
        __syncthreads();
        #pragma unroll
        for (int r = 0; r < 4; ++r) {
            float iv = sigmoidf_(acc[0][r] + xz[0][r]);
            float fv = sigmoidf_(acc[1][r] + xz[1][r]);
            float gv = tanhf_(acc[2][r] + xz[2][r]);
            float ov = sigmoidf_(acc[3][r] + xz[3][r]);
            float cv = fv * c0[r] + iv * gv; c0[r] = cv;
            float hv = ov * tanhf_(cv);
            int j = w * 16 + p, b = q * 4 + r;   // k = j in 0..63
            hdfrag[((j >> 5) * 64 + ((j >> 3) & 3) * 16 + b) * 8 + (j & 7)] = (f16)hv;
        }
        __syncthreads();
        // dec1 gates: K=128 ([h_d0|h_d1], hdfrag kt 0..3)
        f32x4 acc1[4];
        #pragma unroll
        for (int g = 0; g < 4; ++g) acc1[g] = (f32x4){0.f, 0.f, 0.f, 0.f};
        #pragma unroll
        for (int kt = 0; kt < 4; ++kt) {
            f16x8 a = *(const f16x8*)&hdfrag[(kt * 64 + l) * 8];
            #pragma unroll
            for (int g = 0; g < 4; ++g)
                acc1[g] = MFMA16(a, ((const f16x8*)pkD1)[(((g * 4 + w) * 4 + kt) * 64) + l], acc1[g]);
        }
        __syncthreads();
        #pragma unroll
        for (int r = 0; r < 4; ++r) {
            float iv = sigmoidf_(acc1[0][r] + bs1[0]);
            float fv = sigmoidf_(acc1[1][r] + bs1[1]);
            float gv = tanhf_(acc1[2][r] + bs1[2]);
            float ov = sigmoidf_(acc1[3][r] + bs1[3]);
            float cv = fv * c1[r] + iv * gv; c1[r] = cv;
            float hv = ov * tanhf_(cv);
            int j = w * 16 + p, b = q * 4 + r;
            int k = 64 + j;                      // h_d1 lives at k 64..127
            hdfrag[((k >> 5) * 64 + ((k >> 3) & 3) * 16 + b) * 8 + (k & 7)] = (f16)hv;
        }
        __syncthreads();
        // output projection: out_t = h_d1 @ outW^T + out_b (hdfrag kt 2..3)
        f32x4 acco[4];
        #pragma unroll
        for (int i = 0; i < 4; ++i) acco[i] = (f32x4){0.f, 0.f, 0.f, 0.f};
        #pragma unroll
        for (int kt = 0; kt < 2; ++kt) {
            f16x8 a = *(const f16x8*)&hdfrag[((2 + kt) * 64 + l) * 8];
            #pragma unroll
            for (int i = 0; i < 4; ++i)
                acco[i] = MFMA16(a, ((const f16x8*)pkOut)[(((w * 4 + i) * 2 + kt) * 64) + l], acco[i]);
        }
        #pragma unroll
        for (int i = 0; i < 4; ++i)
            #pragma unroll
            for (int r = 0; r < 4; ++r)
                out[((long)(b0 + q * 4 + r) * T + t) * 256 + (w * 4 + i) * 16 + p] = acco[i][r] + bso[i];
    }
}

extern "C" void kernel_launch(void* const* d_in, const int* in_sizes, int n_in,
                              void* d_out, int out_size, void* d_ws, size_t ws_size,
                              hipStream_t stream)
{
    const float* x    = (const float*)d_in[0];
    const float* inW  = (const float*)d_in[1];
    const float* inb  = (const float*)d_in[2];
    const float* e0i  = (const float*)d_in[3];
    const float* e0h  = (const float*)d_in[4];
    const float* eb0i = (const float*)d_in[5];
    const float* eb0h = (const float*)d_in[6];
    const float* e1i  = (const float*)d_in[7];
    const float* e1h  = (const float*)d_in[8];
    const float* eb1i = (const float*)d_in[9];
    const float* eb1h = (const float*)d_in[10];
    const float* d0i  = (const float*)d_in[11];
    const float* d0h  = (const float*)d_in[12];
    const float* db0i = (const float*)d_in[13];
    const float* db0h = (const float*)d_in[14];
    const float* d1i  = (const float*)d_in[15];
    const float* d1h  = (const float*)d_in[16];
    const float* db1i = (const float*)d_in[17];
    const float* db1h = (const float*)d_in[18];
    const float* outW = (const float*)d_in[19];
    const float* outb = (const float*)d_in[20];

    char* ws = (char*)d_ws;
    f16*   pk     = (f16*)ws;
    float* biases = (float*)(ws + BIAS_OFF);
    f16*   h0     = (f16*)(ws + H0_OFF);
    f16*   h1     = (f16*)(ws + H1_OFF);
    f16*   zb     = (f16*)(ws + Z_OFF);
    float* out    = (float*)d_out;

    pack_kernel<<<498, 256, 0, stream>>>(inW, e0i, e0h, e1i, e1h, d0i, d0h, d1i, d1h, outW,
                                         eb0i, eb0h, eb1i, eb1h, db0i, db0h, db1i, db1h,
                                         pk, biases);
    inproj_kernel<<<6400, 256, 0, stream>>>(x, pk, inb, h0);
    lstm_enc_kernel<2, true ><<<64, 1024, 0, stream>>>(h0, pk + 16384, biases, h1, nullptr);
    lstm_enc_kernel<8, false><<<64, 1024, 0, stream>>>(h1, pk + 344064, biases + 1024, nullptr, zb);
    lstm_dec_kernel<<<64, 256, 0, stream>>>(zb, pk + 868352, pk + 933888, pk + 950272, pk + 983040,
                                            biases + 2048, biases + 2304, outb, out);
}